// Round 2
// baseline (2435.870 us; speedup 1.0000x reference)
//
#include <hip/hip_runtime.h>
#include <hip/hip_bf16.h>

#define TT 512
#define BB 64
#define EE 512
#define HH 1024

typedef __attribute__((ext_vector_type(8))) short short8;
typedef __attribute__((ext_vector_type(4))) float f32x4;
typedef __attribute__((ext_vector_type(4))) unsigned int u32x4;

// workspace layout (bytes)
//  X      : [T][B][E] bf16             = 33,554,432
//  Wt     : [256 ct][48 kk][512] bf16  = 12,582,912   (MFMA B-frag order)
//  hbuf   : [2][B][H] bf16             =    262,144
//  flags  : [T][4 rg][64 cg][4] int    =  2,097,152   (16B-strided, R2 layout)
//  probe  : [16] int                   =         64
#define WS_X     0
#define WS_WT    33554432
#define WS_HBUF  46137344
#define WS_FLAGS 46399488
#define WS_PROBE 48496640

static __device__ __forceinline__ unsigned short f2bf(float x) {
    unsigned int u = __float_as_uint(x);
    unsigned int r = (u + 0x7fffu + ((u >> 16) & 1u)) >> 16;
    return (unsigned short)r;
}

// relaxed agent-scope atomics (proven R2 path)
static __device__ __forceinline__ int fl_ld(const int* p) {
    return __hip_atomic_load(p, __ATOMIC_RELAXED, __HIP_MEMORY_SCOPE_AGENT);
}
static __device__ __forceinline__ void fl_st(int* p, int v) {
    __hip_atomic_store(p, v, __ATOMIC_RELAXED, __HIP_MEMORY_SCOPE_AGENT);
}

// ---------------- embedding gather -> bf16 X[t][b][e] ----------------
__global__ void embed_k(const int* __restrict__ src, const float* __restrict__ emb,
                        unsigned short* __restrict__ X) {
    int idx  = blockIdx.x * 256 + threadIdx.x;   // one float4 per thread
    int base = idx * 4;                          // = t*32768 + b*512 + e
    int t = base >> 15;
    int r = base & 32767;
    int b = r >> 9;
    int e = r & 511;
    int v = src[b * TT + t];
    float4 f = *(const float4*)(emb + (size_t)v * EE + e);
    ushort4 s;
    s.x = f2bf(f.x); s.y = f2bf(f.y); s.z = f2bf(f.z); s.w = f2bf(f.w);
    *(ushort4*)(X + base) = s;
}

// ------- weight transpose/convert into MFMA B-fragment order -------
// Wt[((ct*48+kk)*64+lane)*8+j] = Wcomb[k = kk*32+(lane>>4)*8+j][col = ct*16+(lane&15)]
__global__ void wprep_k(const float* __restrict__ Wih, const float* __restrict__ Whh,
                        unsigned short* __restrict__ Wt, int* __restrict__ probe) {
    const int bid = blockIdx.x;          // = ct*48 + kk
    const int kk  = bid % 48;
    const int ct  = bid / 48;
    const int tid = threadIdx.x;

    // diagnostic probe (harmless, validated in R0): asm idioms execute fine
    if (bid == 0 && tid == 0) {
        int xcd;
        asm volatile("s_getreg_b32 %0, hwreg(HW_REG_XCC_ID)" : "=s"(xcd));
        int* pr = probe;
        asm volatile("global_store_dword %0, %1, off sc0"
                     :: "v"(pr), "v"(xcd) : "memory");
        int v;
        asm volatile("global_load_dword %0, %1, off sc0\n\ts_waitcnt vmcnt(0)"
                     : "=v"(v) : "v"(pr) : "memory");
        pr[1] = v;
    }

    const int k0 = kk * 32, c0 = ct * 16;
    __shared__ float tile[32][17];
    for (int e = tid; e < 512; e += 256) {
        int kr = e >> 4, cc = e & 15;
        int k = k0 + kr;
        float v = (k < EE) ? Wih[(size_t)k * 4096 + c0 + cc]
                           : Whh[(size_t)(k - EE) * 4096 + c0 + cc];
        tile[kr][cc] = v;
    }
    __syncthreads();
    for (int e = tid; e < 512; e += 256) {
        int lane = e >> 3, j = e & 7;
        float v = tile[(lane >> 4) * 8 + j][lane & 15];
        Wt[(size_t)bid * 512 + e] = f2bf(v);
    }
}

// ---------------- persistent recurrent kernel ----------------
// 256 WGs = 4 row-groups (16 batch rows) x 64 col-groups (16 hidden units).
// Weights resident in VGPR/AGPR: wave w holds kk = 4i+w (i=0..11) x 4 gates.
// v3: v2's wide sc0sc1 h-exchange + x-prefetch + raw barriers, but flags
// restored to R2's per-producer 16B-strided layout (plain atomic store
// publish, per-lane divergent poll) -- no single-line RMW contention.
__global__ __launch_bounds__(256, 1) void lstm_k(
    const unsigned short* __restrict__ X,
    const unsigned short* __restrict__ Wt,
    const float* __restrict__ bias,
    unsigned short* __restrict__ hbuf,
    int* __restrict__ flags,
    float* __restrict__ out)
{
    const int g        = blockIdx.x;
    const int cg       = g & 63;
    const int rg       = g >> 6;
    const int row_base = rg * 16;
    const int ubase    = cg * 16;
    const int tid  = threadIdx.x;
    const int wave = tid >> 6;
    const int lane = tid & 63;
    const int lrow = lane & 15;
    const int quad = lane >> 4;
    const int erow = tid >> 4, eu = tid & 15;

    __shared__ float zred[4][4][16][17];      // [wave][gate][m-row][n-col]

    // bias in registers: gate layout b[g*HH + unit]
    const float bi_ = bias[          ubase + eu];
    const float bf_ = bias[HH      + ubase + eu];
    const float bg_ = bias[2 * HH  + ubase + eu];
    const float bo_ = bias[3 * HH  + ubase + eu];

    // resident weight fragments
    short8 wr[12][4];
#pragma unroll
    for (int i = 0; i < 12; ++i) {
        const int kk = i * 4 + wave;
#pragma unroll
        for (int g4 = 0; g4 < 4; ++g4) {
            const int ct = g4 * 64 + cg;
            wr[i][g4] = *(const short8*)(Wt + ((size_t)(ct * 48 + kk)) * 512 + lane * 8);
        }
    }

    // per-thread persistent cell state: thread owns (row = tid>>4, u = tid&15)
    float creg = 0.f;

    // x-fragment prefetch registers: loaded one step ahead. RAW for step t+1
    // is enforced by the explicit vmcnt(0) after the poll (and vmcnt(8) at t=0).
    short8 ax[4];
    {
        const unsigned short* xp = X + ((size_t)row_base + lrow) * EE + quad * 8;
#pragma unroll
        for (int i = 0; i < 4; ++i)
            asm volatile("global_load_dwordx4 %0, %1, off"
                         : "=v"(ax[i]) : "v"(xp + (i * 4 + wave) * 32) : "memory");
    }

    for (int t = 0; t < TT; ++t) {
        // ---- wait for h(t-1): every wave polls lane-strided per-producer
        // flags (lane l waits on producer cg=l of this rg). Divergent
        // per-lane spin, R2-proven. s_sleep backoff cuts LLC poll traffic.
        if (t > 0) {
            const int* fp = &flags[(((t - 1) * 4 + rg) << 8) + (lane << 2)];
            while (fl_ld(fp) == 0) { __builtin_amdgcn_s_sleep(1); }
            // drain x-prefetch explicitly (do not rely on compiler waits)
            asm volatile("s_waitcnt vmcnt(0)" ::: "memory");
            __builtin_amdgcn_sched_barrier(0);
        }

        // ---- issue h-loads: one 16B LLC-coherent load per fragment ----
        const unsigned short* hrow = hbuf
            + ((size_t)(((t & 1) ^ 1) * BB) + row_base + lrow) * HH + quad * 8;
        short8 ah[8];
#pragma unroll
        for (int i = 0; i < 8; ++i)
            asm volatile("global_load_dwordx4 %0, %1, off sc0 sc1"
                         : "=v"(ah[i])
                         : "v"(hrow + (size_t)((i * 4 + wave) * 32)) : "memory");

        // t==0: drain the 4 pre-loop x loads (12 outstanding -> keep 8 h-loads)
        asm volatile("s_waitcnt vmcnt(8)" ::: "memory");
        __builtin_amdgcn_sched_barrier(0);

        f32x4 acc0 = {0.f,0.f,0.f,0.f}, acc1 = {0.f,0.f,0.f,0.f};
        f32x4 acc2 = {0.f,0.f,0.f,0.f}, acc3 = {0.f,0.f,0.f,0.f};

        // ---- x-part: kk = 0..15 (prefetched regs, h-loads in flight) ----
#pragma unroll
        for (int i = 0; i < 4; ++i) {
            acc0 = __builtin_amdgcn_mfma_f32_16x16x32_bf16(ax[i], wr[i][0], acc0, 0, 0, 0);
            acc1 = __builtin_amdgcn_mfma_f32_16x16x32_bf16(ax[i], wr[i][1], acc1, 0, 0, 0);
            acc2 = __builtin_amdgcn_mfma_f32_16x16x32_bf16(ax[i], wr[i][2], acc2, 0, 0, 0);
            acc3 = __builtin_amdgcn_mfma_f32_16x16x32_bf16(ax[i], wr[i][3], acc3, 0, 0, 0);
        }

        asm volatile("s_waitcnt vmcnt(0)" ::: "memory");
        __builtin_amdgcn_sched_barrier(0);

        // ---- h-part: kk = 16..47 ----
#pragma unroll
        for (int i = 0; i < 8; ++i) {
            acc0 = __builtin_amdgcn_mfma_f32_16x16x32_bf16(ah[i], wr[i + 4][0], acc0, 0, 0, 0);
            acc1 = __builtin_amdgcn_mfma_f32_16x16x32_bf16(ah[i], wr[i + 4][1], acc1, 0, 0, 0);
            acc2 = __builtin_amdgcn_mfma_f32_16x16x32_bf16(ah[i], wr[i + 4][2], acc2, 0, 0, 0);
            acc3 = __builtin_amdgcn_mfma_f32_16x16x32_bf16(ah[i], wr[i + 4][3], acc3, 0, 0, 0);
        }

        // ---- cross-wave K reduction via LDS (raw barrier: no vmcnt drain,
        //      so the x-prefetch issued last iter stays in flight) ----
#pragma unroll
        for (int r = 0; r < 4; ++r) {
            zred[wave][0][quad * 4 + r][lrow] = acc0[r];
            zred[wave][1][quad * 4 + r][lrow] = acc1[r];
            zred[wave][2][quad * 4 + r][lrow] = acc2[r];
            zred[wave][3][quad * 4 + r][lrow] = acc3[r];
        }
        asm volatile("s_waitcnt lgkmcnt(0)" ::: "memory");
        asm volatile("s_barrier" ::: "memory");

        // ---- gates / cell update (identical arithmetic to passed version) ----
        float zi = zred[0][0][erow][eu] + zred[1][0][erow][eu]
                 + zred[2][0][erow][eu] + zred[3][0][erow][eu] + bi_;
        float zf = zred[0][1][erow][eu] + zred[1][1][erow][eu]
                 + zred[2][1][erow][eu] + zred[3][1][erow][eu] + bf_;
        float zg = zred[0][2][erow][eu] + zred[1][2][erow][eu]
                 + zred[2][2][erow][eu] + zred[3][2][erow][eu] + bg_;
        float zo = zred[0][3][erow][eu] + zred[1][3][erow][eu]
                 + zred[2][3][erow][eu] + zred[3][3][erow][eu] + bo_;
        float iv = 1.f / (1.f + __expf(-zi));
        float fv = 1.f / (1.f + __expf(-zf));
        float gv = 1.f - 2.f / (__expf(2.f * zg) + 1.f);
        float ov = 1.f / (1.f + __expf(-zo));
        float c  = fv * creg + iv * gv;
        creg = c;
        float th = 1.f - 2.f / (__expf(2.f * c) + 1.f);
        float h  = ov * th;

        if (t < TT - 1) {
            // pack 8 adjacent units into one 16B store (lanes eu%8==0)
            float hp1 = __shfl_xor(h, 1);
            unsigned int v01 = (unsigned int)f2bf(h) | ((unsigned int)f2bf(hp1) << 16);
            unsigned int v23 = (unsigned int)__shfl_xor((int)v01, 2);
            unsigned int v45 = (unsigned int)__shfl_xor((int)v01, 4);
            unsigned int v67 = (unsigned int)__shfl_xor((int)v23, 4);
            if ((eu & 7) == 0) {
                u32x4 pk; pk.x = v01; pk.y = v23; pk.z = v45; pk.w = v67;
                unsigned short* hw = hbuf + ((size_t)(t & 1) * BB + row_base + erow) * HH
                                   + ubase + eu;
                asm volatile("global_store_dwordx4 %0, %1, off sc0 sc1"
                             :: "v"(hw), "v"(pk) : "memory");
            }
            // prefetch x for t+1 (flies across the flag flight + poll)
            const unsigned short* xp2 = X + ((size_t)((t + 1) * BB) + row_base + lrow) * EE
                                      + quad * 8;
#pragma unroll
            for (int i = 0; i < 4; ++i)
                asm volatile("global_load_dwordx4 %0, %1, off"
                             : "=v"(ax[i]) : "v"(xp2 + (i * 4 + wave) * 32) : "memory");
            // drain the h-store (oldest, 1 instr/wave) but NOT the 4 prefetches
            asm volatile("s_waitcnt vmcnt(4)" ::: "memory");
        } else {
            out[(row_base + erow) * HH + ubase + eu] = h;             // h_T
            out[BB * HH + (row_base + erow) * HH + ubase + eu] = c;   // c_T
        }

        // raw barrier: all 4 waves have drained their h-stores -> tid0
        // publishes this WG's flag. Also WAR-protects zred for next iter.
        asm volatile("s_barrier" ::: "memory");
        if (t < TT - 1 && tid == 0) {
            fl_st(&flags[((t * 4 + rg) << 8) + (cg << 2)], 1);
        }
    }
}

extern "C" void kernel_launch(void* const* d_in, const int* in_sizes, int n_in,
                              void* d_out, int out_size, void* d_ws, size_t ws_size,
                              hipStream_t stream) {
    const int*   src  = (const int*)d_in[0];
    const float* emb  = (const float*)d_in[1];
    const float* Wih  = (const float*)d_in[2];
    const float* Whh  = (const float*)d_in[3];
    const float* bias = (const float*)d_in[4];
    float* out = (float*)d_out;

    char* ws = (char*)d_ws;
    unsigned short* X     = (unsigned short*)(ws + WS_X);
    unsigned short* Wt    = (unsigned short*)(ws + WS_WT);
    unsigned short* hbuf  = (unsigned short*)(ws + WS_HBUF);
    int*            flags = (int*)(ws + WS_FLAGS);
    int*            probe = (int*)(ws + WS_PROBE);

    hipMemsetAsync(hbuf, 0, 2 * BB * HH * 2, stream);
    hipMemsetAsync(flags, 0, TT * 4 * 64 * 4 * 4, stream);
    embed_k<<<dim3(16384), dim3(256), 0, stream>>>(src, emb, X);
    wprep_k<<<dim3(12288), dim3(256), 0, stream>>>(Wih, Whh, Wt, probe);
    lstm_k<<<dim3(256), dim3(256), 0, stream>>>(X, Wt, bias, hbuf, flags, out);
}

// Round 3
// 1747.834 us; speedup vs baseline: 1.3937x; 1.3937x over previous
//
#include <hip/hip_runtime.h>
#include <hip/hip_bf16.h>

#define TT 512
#define BB 64
#define EE 512
#define HH 1024

typedef __attribute__((ext_vector_type(8))) short short8;
typedef __attribute__((ext_vector_type(4))) float f32x4;
typedef __attribute__((ext_vector_type(4))) unsigned int u32x4;

// workspace layout (bytes)
//  X      : [T][B][E] bf16             = 33,554,432
//  Wt     : [256 ct][48 kk][512] bf16  = 12,582,912   (MFMA B-frag order)
//  hbuf   : [2][B][H] bf16             =    262,144
//  flags  : [T][4 rg][64 cg][4] int    =  2,097,152   (16B-strided, R2 layout)
//  probe  : [16] int                   =         64
#define WS_X     0
#define WS_WT    33554432
#define WS_HBUF  46137344
#define WS_FLAGS 46399488
#define WS_PROBE 48496640

static __device__ __forceinline__ unsigned short f2bf(float x) {
    unsigned int u = __float_as_uint(x);
    unsigned int r = (u + 0x7fffu + ((u >> 16) & 1u)) >> 16;
    return (unsigned short)r;
}

// relaxed agent-scope atomics (proven baseline path, services at LLC)
static __device__ __forceinline__ int fl_ld(const int* p) {
    return __hip_atomic_load(p, __ATOMIC_RELAXED, __HIP_MEMORY_SCOPE_AGENT);
}
static __device__ __forceinline__ void fl_st(int* p, int v) {
    __hip_atomic_store(p, v, __ATOMIC_RELAXED, __HIP_MEMORY_SCOPE_AGENT);
}

// ---------------- embedding gather -> bf16 X[t][b][e] ----------------
__global__ void embed_k(const int* __restrict__ src, const float* __restrict__ emb,
                        unsigned short* __restrict__ X) {
    int idx  = blockIdx.x * 256 + threadIdx.x;   // one float4 per thread
    int base = idx * 4;                          // = t*32768 + b*512 + e
    int t = base >> 15;
    int r = base & 32767;
    int b = r >> 9;
    int e = r & 511;
    int v = src[b * TT + t];
    float4 f = *(const float4*)(emb + (size_t)v * EE + e);
    ushort4 s;
    s.x = f2bf(f.x); s.y = f2bf(f.y); s.z = f2bf(f.z); s.w = f2bf(f.w);
    *(ushort4*)(X + base) = s;
}

// ------- weight transpose/convert into MFMA B-fragment order -------
// Wt[((ct*48+kk)*64+lane)*8+j] = Wcomb[k = kk*32+(lane>>4)*8+j][col = ct*16+(lane&15)]
__global__ void wprep_k(const float* __restrict__ Wih, const float* __restrict__ Whh,
                        unsigned short* __restrict__ Wt, int* __restrict__ probe) {
    const int bid = blockIdx.x;          // = ct*48 + kk
    const int kk  = bid % 48;
    const int ct  = bid / 48;
    const int tid = threadIdx.x;

    // diagnostic probe (harmless, validated): asm idioms execute fine
    if (bid == 0 && tid == 0) {
        int xcd;
        asm volatile("s_getreg_b32 %0, hwreg(HW_REG_XCC_ID)" : "=s"(xcd));
        int* pr = probe;
        asm volatile("global_store_dword %0, %1, off sc0"
                     :: "v"(pr), "v"(xcd) : "memory");
        int v;
        asm volatile("global_load_dword %0, %1, off sc0\n\ts_waitcnt vmcnt(0)"
                     : "=v"(v) : "v"(pr) : "memory");
        pr[1] = v;
    }

    const int k0 = kk * 32, c0 = ct * 16;
    __shared__ float tile[32][17];
    for (int e = tid; e < 512; e += 256) {
        int kr = e >> 4, cc = e & 15;
        int k = k0 + kr;
        float v = (k < EE) ? Wih[(size_t)k * 4096 + c0 + cc]
                           : Whh[(size_t)(k - EE) * 4096 + c0 + cc];
        tile[kr][cc] = v;
    }
    __syncthreads();
    for (int e = tid; e < 512; e += 256) {
        int lane = e >> 3, j = e & 7;
        float v = tile[(lane >> 4) * 8 + j][lane & 15];
        Wt[(size_t)bid * 512 + e] = f2bf(v);
    }
}

// ---------------- persistent recurrent kernel ----------------
// 256 WGs = 4 row-groups (16 batch rows) x 64 col-groups (16 hidden units).
// Weights resident in VGPR/AGPR: wave w holds kk = 4i+w (i=0..11) x 4 gates.
// v4 = R0 proven skeleton + {16B agent-scope (sc1) h-exchange, per-wave
// 16-producer poll (no post-poll barrier), x-MFMA in h-load shadow, reg bias}.
__global__ __launch_bounds__(256, 1) void lstm_k(
    const unsigned short* __restrict__ X,
    const unsigned short* __restrict__ Wt,
    const float* __restrict__ bias,
    unsigned short* __restrict__ hbuf,
    int* __restrict__ flags,
    float* __restrict__ out)
{
    const int g        = blockIdx.x;
    const int cg       = g & 63;
    const int rg       = g >> 6;
    const int row_base = rg * 16;
    const int ubase    = cg * 16;
    const int tid  = threadIdx.x;
    const int wave = tid >> 6;
    const int lane = tid & 63;
    const int lrow = lane & 15;
    const int quad = lane >> 4;
    const int erow = tid >> 4, eu = tid & 15;

    __shared__ float zred[4][4][16][17];      // [wave][gate][m-row][n-col]

    // bias in registers: gate layout b[g*HH + unit]
    const float bi_ = bias[          ubase + eu];
    const float bf_ = bias[HH      + ubase + eu];
    const float bg_ = bias[2 * HH  + ubase + eu];
    const float bo_ = bias[3 * HH  + ubase + eu];

    // resident weight fragments
    short8 wr[12][4];
#pragma unroll
    for (int i = 0; i < 12; ++i) {
        const int kk = i * 4 + wave;
#pragma unroll
        for (int g4 = 0; g4 < 4; ++g4) {
            const int ct = g4 * 64 + cg;
            wr[i][g4] = *(const short8*)(Wt + ((size_t)(ct * 48 + kk)) * 512 + lane * 8);
        }
    }

    // per-wave producer set: fragment (i,wave) covers h-units
    // [(4i+wave)*32, +32) -> producers cg = 8i+2*wave, 8i+2*wave+1.
    // lane idx (0..15) -> producer 8*(idx>>1) + 2*wave + (idx&1).
    const int pidx = lane & 15;
    const int prod = 8 * (pidx >> 1) + 2 * wave + (pidx & 1);

    // per-thread persistent cell state: thread owns (row = tid>>4, u = tid&15)
    float creg = 0.f;

    for (int t = 0; t < TT; ++t) {
        // ---- issue x loads (plain cached); latency hides under the poll ----
        const unsigned short* xp = X + ((size_t)(t * BB) + row_base + lrow) * EE + quad * 8;
        short8 ax[4];
#pragma unroll
        for (int i = 0; i < 4; ++i)
            asm volatile("global_load_dwordx4 %0, %1, off"
                         : "=v"(ax[i]) : "v"(xp + (i * 4 + wave) * 32) : "memory");

        // ---- wait for h(t-1): each wave polls ONLY its 16 producers ----
        // (divergent per-lane spin, proven pattern; no barrier after --
        //  waves proceed independently until the zred reduction barrier)
        if (t > 0) {
            const int* fp = &flags[(((t - 1) * 4 + rg) * 64 + prod) * 4];
            while (fl_ld(fp) == 0) { }
        }

        // ---- issue h-loads: one 16B agent-coherent (sc1) load/fragment ----
        const unsigned short* hrow = hbuf
            + ((size_t)(((t & 1) ^ 1) * BB) + row_base + lrow) * HH + quad * 8;
        short8 ah[8];
#pragma unroll
        for (int i = 0; i < 8; ++i)
            asm volatile("global_load_dwordx4 %0, %1, off sc1"
                         : "=v"(ah[i])
                         : "v"(hrow + (size_t)((i * 4 + wave) * 32)) : "memory");

        // drain x loads (t==0 path; t>0 the poll already drained them),
        // keep the 8 h-loads in flight under the x-MFMAs
        asm volatile("s_waitcnt vmcnt(8)" ::: "memory");
        __builtin_amdgcn_sched_barrier(0);

        f32x4 acc0 = {0.f,0.f,0.f,0.f}, acc1 = {0.f,0.f,0.f,0.f};
        f32x4 acc2 = {0.f,0.f,0.f,0.f}, acc3 = {0.f,0.f,0.f,0.f};

        // ---- x-part: kk = 0..15 (h-loads in flight underneath) ----
#pragma unroll
        for (int i = 0; i < 4; ++i) {
            acc0 = __builtin_amdgcn_mfma_f32_16x16x32_bf16(ax[i], wr[i][0], acc0, 0, 0, 0);
            acc1 = __builtin_amdgcn_mfma_f32_16x16x32_bf16(ax[i], wr[i][1], acc1, 0, 0, 0);
            acc2 = __builtin_amdgcn_mfma_f32_16x16x32_bf16(ax[i], wr[i][2], acc2, 0, 0, 0);
            acc3 = __builtin_amdgcn_mfma_f32_16x16x32_bf16(ax[i], wr[i][3], acc3, 0, 0, 0);
        }

        asm volatile("s_waitcnt vmcnt(0)" ::: "memory");
        __builtin_amdgcn_sched_barrier(0);

        // ---- h-part: kk = 16..47 ----
#pragma unroll
        for (int i = 0; i < 8; ++i) {
            acc0 = __builtin_amdgcn_mfma_f32_16x16x32_bf16(ah[i], wr[i + 4][0], acc0, 0, 0, 0);
            acc1 = __builtin_amdgcn_mfma_f32_16x16x32_bf16(ah[i], wr[i + 4][1], acc1, 0, 0, 0);
            acc2 = __builtin_amdgcn_mfma_f32_16x16x32_bf16(ah[i], wr[i + 4][2], acc2, 0, 0, 0);
            acc3 = __builtin_amdgcn_mfma_f32_16x16x32_bf16(ah[i], wr[i + 4][3], acc3, 0, 0, 0);
        }

        // ---- cross-wave K reduction via LDS ----
#pragma unroll
        for (int r = 0; r < 4; ++r) {
            zred[wave][0][quad * 4 + r][lrow] = acc0[r];
            zred[wave][1][quad * 4 + r][lrow] = acc1[r];
            zred[wave][2][quad * 4 + r][lrow] = acc2[r];
            zred[wave][3][quad * 4 + r][lrow] = acc3[r];
        }
        __syncthreads();

        // ---- gates / cell update (identical arithmetic to passed version) ----
        float zi = zred[0][0][erow][eu] + zred[1][0][erow][eu]
                 + zred[2][0][erow][eu] + zred[3][0][erow][eu] + bi_;
        float zf = zred[0][1][erow][eu] + zred[1][1][erow][eu]
                 + zred[2][1][erow][eu] + zred[3][1][erow][eu] + bf_;
        float zg = zred[0][2][erow][eu] + zred[1][2][erow][eu]
                 + zred[2][2][erow][eu] + zred[3][2][erow][eu] + bg_;
        float zo = zred[0][3][erow][eu] + zred[1][3][erow][eu]
                 + zred[2][3][erow][eu] + zred[3][3][erow][eu] + bo_;
        float iv = 1.f / (1.f + __expf(-zi));
        float fv = 1.f / (1.f + __expf(-zf));
        float gv = 1.f - 2.f / (__expf(2.f * zg) + 1.f);
        float ov = 1.f / (1.f + __expf(-zo));
        float c  = fv * creg + iv * gv;
        creg = c;
        float th = 1.f - 2.f / (__expf(2.f * c) + 1.f);
        float h  = ov * th;

        if (t < TT - 1) {
            // pack 8 adjacent units into one 16B agent-scope store
            float hp1 = __shfl_xor(h, 1);
            unsigned int v01 = (unsigned int)f2bf(h) | ((unsigned int)f2bf(hp1) << 16);
            unsigned int v23 = (unsigned int)__shfl_xor((int)v01, 2);
            unsigned int v45 = (unsigned int)__shfl_xor((int)v01, 4);
            unsigned int v67 = (unsigned int)__shfl_xor((int)v23, 4);
            if ((eu & 7) == 0) {
                u32x4 pk; pk.x = v01; pk.y = v23; pk.z = v45; pk.w = v67;
                unsigned short* hw = hbuf + ((size_t)(t & 1) * BB + row_base + erow) * HH
                                   + ubase + eu;
                asm volatile("global_store_dwordx4 %0, %1, off sc1"
                             :: "v"(hw), "v"(pk) : "memory");
            }
        } else {
            out[(row_base + erow) * HH + ubase + eu] = h;             // h_T
            out[BB * HH + (row_base + erow) * HH + ubase + eu] = c;   // c_T
        }

        // proven drain+publish: __syncthreads emits vmcnt(0) before s_barrier
        // -> all waves' h-stores are at the LLC before tid0 publishes.
        // Also WAR-protects zred for the next iteration.
        __syncthreads();
        if (t < TT - 1 && tid == 0) {
            fl_st(&flags[((t * 4 + rg) * 64 + cg) * 4], 1);
        }
    }
}

extern "C" void kernel_launch(void* const* d_in, const int* in_sizes, int n_in,
                              void* d_out, int out_size, void* d_ws, size_t ws_size,
                              hipStream_t stream) {
    const int*   src  = (const int*)d_in[0];
    const float* emb  = (const float*)d_in[1];
    const float* Wih  = (const float*)d_in[2];
    const float* Whh  = (const float*)d_in[3];
    const float* bias = (const float*)d_in[4];
    float* out = (float*)d_out;

    char* ws = (char*)d_ws;
    unsigned short* X     = (unsigned short*)(ws + WS_X);
    unsigned short* Wt    = (unsigned short*)(ws + WS_WT);
    unsigned short* hbuf  = (unsigned short*)(ws + WS_HBUF);
    int*            flags = (int*)(ws + WS_FLAGS);
    int*            probe = (int*)(ws + WS_PROBE);

    hipMemsetAsync(hbuf, 0, 2 * BB * HH * 2, stream);
    hipMemsetAsync(flags, 0, TT * 4 * 64 * 4 * 4, stream);
    embed_k<<<dim3(16384), dim3(256), 0, stream>>>(src, emb, X);
    wprep_k<<<dim3(12288), dim3(256), 0, stream>>>(Wih, Whh, Wt, probe);
    lstm_k<<<dim3(256), dim3(256), 0, stream>>>(X, Wt, bias, hbuf, flags, out);
}